// Round 5
// baseline (176.435 us; speedup 1.0000x reference)
//
#include <hip/hip_runtime.h>

#define NG 76
#define NPOS (NG * NG)            // 5776
#define NC 85                     // 5 + 80
#define NA 3
#define NPLANES 48                // 16 batches * 3 anchors
#define PPB 16                    // positions per tile (divides 5776)
#define TPP (NPOS / PPB)          // 361 tiles per plane
#define NTILES (NPLANES * TPP)    // 17328
#define ROWV (PPB / 4)            // 4 float4 per channel row
#define NV (NC * ROWV)            // 340 float4 per tile
#define BLK 256
#define GRID 2048                 // 8 blocks/CU * 256 CU
#define STRIDE_F 8.0f             // 608 / 76

typedef float floatx4 __attribute__((ext_vector_type(4)));

// exp(w) * scaled_anchor * stride == exp(w) * ANCHOR
__constant__ float c_aw[NA] = {10.0f, 16.0f, 33.0f};
__constant__ float c_ah[NA] = {13.0f, 30.0f, 23.0f};

__device__ __forceinline__ float fsig(float x) {
    return __builtin_amdgcn_rcpf(1.0f + __expf(-x));
}

__global__ __launch_bounds__(BLK, 8) void det_kernel(const float* __restrict__ in,
                                                     float* __restrict__ out) {
    // LDS tile in OUTPUT order: idx = p*NC + c
    __shared__ float lds[PPB * NC];

    const int b = blockIdx.x;
    // balanced contiguous chunk of tiles per block (base=8, rem=944)
    const int base = NTILES / GRID;
    const int rem  = NTILES % GRID;
    int t0, cnt;
    if (b < rem) { cnt = base + 1; t0 = b * (base + 1); }
    else         { cnt = base;     t0 = rem + b * base; }

    const int t = threadIdx.x;

    // per-thread load/compute descriptors (two rounds: v0 = t, v1 = t+BLK)
    const int c0v = t >> 2, pq0 = t & 3;
    const int v1  = t + BLK;
    const int c1v = v1 >> 2, pq1 = v1 & 3;
    const bool has1 = (v1 < NV);                 // t < 84
    const int goff0 = c0v * NPOS + pq0 * 4;      // global offsets within a tile
    const int goff1 = c1v * NPOS + pq1 * 4;
    const int lb0   = (pq0 * 4) * NC + c0v;      // LDS scatter bases
    const int lb1   = (pq1 * 4) * NC + c1v;

    floatx4 r0, r1;

    // ---- prologue: load tile t0 ----
    {
        const int plane = t0 / TPP;
        const int tl    = t0 - plane * TPP;
        const float* ip = in + (size_t)plane * (NC * NPOS) + tl * PPB;
        r0 = *reinterpret_cast<const floatx4*>(ip + goff0);
        if (has1) r1 = *reinterpret_cast<const floatx4*>(ip + goff1);
    }

    for (int i = 0; i < cnt; ++i) {
        const int tid   = t0 + i;
        const int plane = tid / TPP;
        const int tl    = tid - plane * TPP;
        const int a     = plane % NA;

        __syncthreads();        // previous iteration's LDS readers done

        // ---- scatter current tile regs -> LDS (output order) ----
        lds[lb0 + 0 * NC] = r0.x;
        lds[lb0 + 1 * NC] = r0.y;
        lds[lb0 + 2 * NC] = r0.z;
        lds[lb0 + 3 * NC] = r0.w;
        if (has1) {
            lds[lb1 + 0 * NC] = r1.x;
            lds[lb1 + 1 * NC] = r1.y;
            lds[lb1 + 2 * NC] = r1.z;
            lds[lb1 + 3 * NC] = r1.w;
        }

        // ---- prefetch NEXT tile's loads (stay in flight through store phase) ----
        if (i + 1 < cnt) {
            const int ntid   = tid + 1;
            const int nplane = ntid / TPP;
            const int ntl    = ntid - nplane * TPP;
            const float* ip  = in + (size_t)nplane * (NC * NPOS) + ntl * PPB;
            r0 = *reinterpret_cast<const floatx4*>(ip + goff0);
            if (has1) r1 = *reinterpret_cast<const floatx4*>(ip + goff1);
        }

        __syncthreads();        // scatter visible to all

        // ---- compute + contiguous store ----
        const float aw = c_aw[a];
        const float ah = c_ah[a];
        float* ob = out + (size_t)plane * (NPOS * NC) + (size_t)tl * (PPB * NC);
        const int posbase = tl * PPB;

        #pragma unroll
        for (int rnd = 0; rnd < 2; ++rnd) {
            const int v = t + rnd * BLK;
            if (rnd == 1 && !has1) break;
            const int e0 = 4 * v;
            const floatx4 f = *reinterpret_cast<const floatx4*>(&lds[e0]);
            float xin[4] = {f.x, f.y, f.z, f.w};
            float res[4];
            int p = e0 / NC;
            int c = e0 - p * NC;
            #pragma unroll
            for (int k = 0; k < 4; ++k) {
                const float x = xin[k];
                float rr;
                if (c >= 4) {                    // conf + 80 classes
                    rr = fsig(x);
                } else if (c == 2) {             // box w
                    rr = __expf(x) * aw;
                } else if (c == 3) {             // box h
                    rr = __expf(x) * ah;
                } else {                         // box x / y
                    const int pos = posbase + p;
                    const int gy  = pos / NG;
                    const int gx  = pos - gy * NG;
                    const float g = (c == 0) ? (float)gx : (float)gy;
                    rr = (fsig(x) + g) * STRIDE_F;
                }
                res[k] = rr;
                if (++c == NC) { c = 0; ++p; }
            }
            floatx4 o;
            o.x = res[0]; o.y = res[1]; o.z = res[2]; o.w = res[3];
            *reinterpret_cast<floatx4*>(ob + e0) = o;
        }
    }
}

extern "C" void kernel_launch(void* const* d_in, const int* in_sizes, int n_in,
                              void* d_out, int out_size, void* d_ws, size_t ws_size,
                              hipStream_t stream) {
    const float* x = (const float*)d_in[0];
    float* out     = (float*)d_out;
    det_kernel<<<GRID, BLK, 0, stream>>>(x, out);
}